// Round 5
// baseline (1935.912 us; speedup 1.0000x reference)
//
#include <hip/hip_runtime.h>
#include <math.h>

// Problem constants
static const int BSZ   = 8;
static const int SLN   = 100;
static const int NNODE = 200;
static const int NEDGE = 600;
static const int CP1N  = 111;
static const int DIM   = 128;
static const int DCN   = 64;
static const int HID   = 256;
static const int FEATN = 177;   // CP1N + DCN + 2
static const int GN    = 800;   // BS*SL
static const int MROW  = 160000; // GN*NNODE

typedef unsigned short u16;
typedef u16    u16x8  __attribute__((ext_vector_type(8)));
typedef __bf16 bf16x8 __attribute__((ext_vector_type(8)));
typedef __bf16 bf16x2 __attribute__((ext_vector_type(2)));
typedef float  f32x16 __attribute__((ext_vector_type(16)));

#if defined(__has_builtin)
# if __has_builtin(__builtin_amdgcn_fdot2_f32_bf16)
#  define HAVE_FDOT2 1
# else
#  define HAVE_FDOT2 0
# endif
#else
# define HAVE_FDOT2 0
#endif

__device__ __forceinline__ float sigf(float v){ return 1.0f/(1.0f + expf(-v)); }
__device__ __forceinline__ u16 f2bf(float f){
    union { float f; unsigned u; } v; v.f = f;
    unsigned r = v.u + 0x7FFFu + ((v.u >> 16) & 1u);
    return (u16)(r >> 16);
}
__device__ __forceinline__ float bf2f(u16 u){
    union { unsigned u; float f; } v; v.u = ((unsigned)u) << 16;
    return v.f;
}
__device__ __forceinline__ float dot2bf(unsigned w, unsigned h, float acc){
#if HAVE_FDOT2
    return __builtin_amdgcn_fdot2_f32_bf16(__builtin_bit_cast(bf16x2, w),
                                           __builtin_bit_cast(bf16x2, h), acc, false);
#else
    acc += bf2f((u16)(w & 0xffffu)) * bf2f((u16)(h & 0xffffu));
    acc += bf2f((u16)(w >> 16))     * bf2f((u16)(h >> 16));
    return acc;
#endif
}

// ---------------------------------------------------------------------------
// whhP[k2][j] = packed bf16 pair (Whh[j][2k2], Whh[j][2k2+1]);  WihT[k][j] = Wih[j][k] fp32
__global__ void k_transpose_w(const float* __restrict__ whh, const float* __restrict__ wih,
                              unsigned* __restrict__ whhP, float* __restrict__ wihT){
    int idx = blockIdx.x*blockDim.x + threadIdx.x;
    const int total1 = 128*1024;
    if (idx < total1){
        int k2 = idx >> 10, j = idx & 1023;
        u16 lo = f2bf(whh[(size_t)j*256 + 2*k2]);
        u16 hi = f2bf(whh[(size_t)j*256 + 2*k2 + 1]);
        whhP[(size_t)k2*1024 + j] = (unsigned)lo | ((unsigned)hi << 16);
    }
    int idx2 = idx - total1;
    const int total2 = FEATN*1024;
    if (idx2 >= 0 && idx2 < total2){
        int k = idx2 >> 10, j = idx2 & 1023;
        wihT[(size_t)k*1024 + j] = wih[(size_t)j*FEATN + k];
    }
}

// ---------------------------------------------------------------------------
// bf16 weight conversions: wih/whh (GRU, natural layout), gwT (transposed ggnn), tw (natural)
__global__ void k_convert_w(const float* __restrict__ wih, const float* __restrict__ whh,
                            const float* __restrict__ gw, const float* __restrict__ tw,
                            u16* __restrict__ wihb, u16* __restrict__ whhb,
                            u16* __restrict__ gwTb, u16* __restrict__ twb){
    int idx = blockIdx.x*blockDim.x + threadIdx.x;
    if (idx < 49152){
        wihb[idx] = f2bf(wih[idx]);
    } else if (idx < 98304){
        int t = idx - 49152;
        whhb[t] = f2bf(whh[t]);
    } else if (idx < 163840){
        int t = idx - 98304;
        int l = t >> 14, rem = t & 16383, n = rem >> 7, k = rem & 127;
        gwTb[t] = f2bf(gw[((size_t)l*128 + k)*128 + n]);
    } else if (idx < 172032){
        int t = idx - 163840;
        twb[t] = f2bf(tw[t]);
    }
}

// ---------------------------------------------------------------------------
// Per-graph CSR over dst + per-edge weight = mean(edge_embed_w[type])
__global__ void __launch_bounds__(256)
k_build_csr(const int* __restrict__ edge, const int* __restrict__ etype,
            const float* __restrict__ eembed,
            int* __restrict__ csr_src, float* __restrict__ csr_w, int* __restrict__ csr_off){
    int g = blockIdx.x; int tid = threadIdx.x;
    __shared__ float tmean[8];
    __shared__ float tpart[8][32];
    __shared__ int cnt[NNODE];
    __shared__ int offs[NNODE+1];
    __shared__ int cur[NNODE];
    {
        int ty = tid >> 5, lane = tid & 31;
        float s = 0.f;
        for (int i = lane; i < DIM; i += 32) s += eembed[ty*DIM + i];
        tpart[ty][lane] = s;
    }
    for (int i = tid; i < NNODE; i += 256) cnt[i] = 0;
    __syncthreads();
    if (tid < 8){
        float s = 0.f;
        for (int i = 0; i < 32; i++) s += tpart[tid][i];
        tmean[tid] = s / (float)DIM;
    }
    for (int e = tid; e < NEDGE; e += 256){
        int dst = edge[((size_t)g*2+1)*NEDGE + e];
        atomicAdd(&cnt[dst], 1);
    }
    __syncthreads();
    if (tid == 0){
        int run = 0;
        for (int i = 0; i < NNODE; i++){ offs[i] = run; run += cnt[i]; }
        offs[NNODE] = run;
    }
    __syncthreads();
    for (int i = tid; i < NNODE; i += 256) cur[i] = offs[i];
    for (int i = tid; i < NNODE+1; i += 256) csr_off[(size_t)g*(NNODE+1)+i] = offs[i];
    __syncthreads();
    for (int e = tid; e < NEDGE; e += 256){
        int dst = edge[((size_t)g*2+1)*NEDGE + e];
        int src = edge[((size_t)g*2+0)*NEDGE + e];
        float w = tmean[etype[(size_t)g*NEDGE + e]];
        int pos = atomicAdd(&cur[dst], 1);
        csr_src[(size_t)g*NEDGE + pos] = src;
        csr_w [(size_t)g*NEDGE + pos] = w;
    }
}

// ---------------------------------------------------------------------------
// xb = bf16(node_embed_w[node_id])
__global__ void k_gather_x(const int* __restrict__ nid, const float4* __restrict__ emb,
                           u16x8* __restrict__ xb){
    const long total = (long)MROW*16;   // 8-element chunks
    for (long c = (long)blockIdx.x*blockDim.x + threadIdx.x; c < total; c += (long)gridDim.x*blockDim.x){
        long row = c >> 4; int p = (int)(c & 15);
        float4 a = emb[(size_t)nid[row]*32 + p*2];
        float4 b = emb[(size_t)nid[row]*32 + p*2 + 1];
        u16x8 v;
        v[0]=f2bf(a.x); v[1]=f2bf(a.y); v[2]=f2bf(a.z); v[3]=f2bf(a.w);
        v[4]=f2bf(b.x); v[5]=f2bf(b.y); v[6]=f2bf(b.z); v[7]=f2bf(b.w);
        xb[c] = v;
    }
}

// ---------------------------------------------------------------------------
// MFMA m = x_g @ W (A-frags straight from global), m in LDS bf16, CSR scatter -> aggb
__global__ void __launch_bounds__(256)
k_mm_scatter(const u16* __restrict__ xb, const u16* __restrict__ gwTb_l,
             const int* __restrict__ csr_src, const float* __restrict__ csr_w,
             const int* __restrict__ csr_off, u16* __restrict__ aggb){
    __shared__ u16 m_s[224*128];       // bf16 m, 57344 B
    int g = blockIdx.x;
    int tid = threadIdx.x;
    const u16x8* xg = (const u16x8*)(xb + (size_t)g*NNODE*DIM);
    int w = tid >> 6, lane = tid & 63;
    int nbase = w*32;
    int m = lane & 31, kh = lane >> 5;
    f32x16 acc[7];
    #pragma unroll
    for (int t = 0; t < 7; t++) acc[t] = (f32x16)0.f;
    const u16x8* bp = (const u16x8*)gwTb_l;
    int nrow = nbase + m;
    #pragma unroll
    for (int kc = 0; kc < 8; kc++){
        u16x8 b = bp[nrow*16 + kc*2 + kh];
        #pragma unroll
        for (int mt = 0; mt < 7; mt++){
            int arow = mt*32 + m;
            u16x8 a = {};
            if (arow < NNODE) a = xg[arow*16 + kc*2 + kh];
            acc[mt] = __builtin_amdgcn_mfma_f32_32x32x16_bf16(
                __builtin_bit_cast(bf16x8, a), __builtin_bit_cast(bf16x8, b), acc[mt], 0, 0, 0);
        }
    }
    // Write m to LDS as bf16
    #pragma unroll
    for (int mt = 0; mt < 7; mt++){
        #pragma unroll
        for (int r = 0; r < 16; r++){
            int row = mt*32 + (r&3) + 8*(r>>2) + 4*kh;
            int col = nbase + m;
            m_s[row*128 + col] = f2bf(acc[mt][r]);
        }
    }
    __syncthreads();
    // CSR scatter: agg[n][j] = sum_p w[p] * m[src[p]][j]
    const int*   off  = csr_off + (size_t)g*(NNODE+1);
    const int*   srcp = csr_src + (size_t)g*NEDGE;
    const float* wp   = csr_w   + (size_t)g*NEDGE;
    int j = tid & 127, rg = tid >> 7;
    for (int i = 0; i < 100; i++){
        int n = rg*100 + i;
        int b = off[n], e = off[n+1];
        float a = 0.f;
        for (int p = b; p < e; p++) a += wp[p] * bf2f(m_s[srcp[p]*128 + j]);
        aggb[((size_t)g*NNODE + n)*DIM + j] = f2bf(a);
    }
}

// ---------------------------------------------------------------------------
// Fused MFMA GRU layer. Grid 2500 x 512 threads. M-tile 64 rows. State is bf16 xb.
__global__ void __launch_bounds__(512)
k_gru_mfma(u16* __restrict__ xb, const u16* __restrict__ aggb,
           const u16* __restrict__ wihb, const u16* __restrict__ whhb,
           const float* __restrict__ bih, const float* __restrict__ bhh){
    __shared__ u16x8 afragA[1024];   // agg fragments [mtile2][kc8][lane64]
    __shared__ u16x8 afragX[1024];   // x fragments
    int tid = threadIdx.x;
    long r0 = (long)blockIdx.x * 64;
    // Stage A fragments
    const u16x8* aggp = (const u16x8*)aggb;
    const u16x8* xbp  = (const u16x8*)xb;
    for (int c = tid; c < 2048; c += 512){
        int mat = c >> 10, cc = c & 1023;
        int row = cc >> 4, kc8 = cc & 15;
        u16x8 v = (mat ? xbp : aggp)[(r0 + row)*16 + kc8];
        int slot = ((row>>5)*8 + (kc8>>1))*64 + (row&31) + 32*(kc8&1);
        (mat ? afragX : afragA)[slot] = v;
    }
    __syncthreads();
    int w = tid >> 6, lane = tid & 63;
    int mt = w >> 2;               // 0..1
    int cb = (w & 3) * 32;         // col base within 128
    f32x16 acc[6];
    #pragma unroll
    for (int t = 0; t < 6; t++) acc[t] = (f32x16)0.f;
    const u16x8* bi = (const u16x8*)wihb;
    const u16x8* bh = (const u16x8*)whhb;
    int kh = lane >> 5;
    int ncol = cb + (lane & 31);
    #pragma unroll
    for (int kc = 0; kc < 8; kc++){
        u16x8 aA = afragA[(mt*8 + kc)*64 + lane];
        u16x8 aX = afragX[(mt*8 + kc)*64 + lane];
        #pragma unroll
        for (int g3 = 0; g3 < 3; g3++){
            int n = g3*128 + ncol;
            u16x8 b1 = bi[n*16 + kc*2 + kh];
            u16x8 b2 = bh[n*16 + kc*2 + kh];
            acc[g3]   = __builtin_amdgcn_mfma_f32_32x32x16_bf16(
                __builtin_bit_cast(bf16x8, aA), __builtin_bit_cast(bf16x8, b1), acc[g3], 0,0,0);
            acc[3+g3] = __builtin_amdgcn_mfma_f32_32x32x16_bf16(
                __builtin_bit_cast(bf16x8, aX), __builtin_bit_cast(bf16x8, b2), acc[3+g3], 0,0,0);
        }
    }
    // GRU elementwise in fp32 from bf16 inputs
    int col = cb + (lane & 31);
    float bir = bih[col], biz = bih[col+128], bin = bih[col+256];
    float bhr = bhh[col], bhz = bhh[col+128], bhn = bhh[col+256];
    #pragma unroll
    for (int r = 0; r < 16; r++){
        int row = mt*32 + (r&3) + 8*(r>>2) + 4*kh;
        size_t gi_ = (size_t)(r0 + row)*DIM + col;
        float xo = bf2f(xb[gi_]);
        float rr  = sigf(acc[0][r] + bir + acc[3][r] + bhr);
        float zz  = sigf(acc[1][r] + biz + acc[4][r] + bhz);
        float nn_ = tanhf(acc[2][r] + bin + rr*(acc[5][r] + bhn));
        float xn  = (1.f - zz)*nn_ + zz*xo;
        xb[gi_]  = f2bf(xn);
    }
}

// ---------------------------------------------------------------------------
// ggnn_out = x @ transdim_w^T via MFMA (M x 64 fp32 out, K=128). Grid 1250 x 256.
__global__ void __launch_bounds__(256)
k_transdim(const u16* __restrict__ xb, const u16* __restrict__ twb, float* __restrict__ out){
    int tid = threadIdx.x;
    int w = tid >> 6, lane = tid & 63;
    int m = lane & 31, kh = lane >> 5;
    long r0 = (long)blockIdx.x * 128;
    const u16x8* xp = (const u16x8*)xb;
    const u16x8* tp = (const u16x8*)twb;
    long rowA = r0 + w*32 + m;
    f32x16 acc[2];
    acc[0] = (f32x16)0.f; acc[1] = (f32x16)0.f;
    #pragma unroll
    for (int kc = 0; kc < 8; kc++){
        u16x8 a = xp[rowA*16 + kc*2 + kh];
        #pragma unroll
        for (int nt = 0; nt < 2; nt++){
            u16x8 b = tp[(nt*32 + m)*16 + kc*2 + kh];
            acc[nt] = __builtin_amdgcn_mfma_f32_32x32x16_bf16(
                __builtin_bit_cast(bf16x8, a), __builtin_bit_cast(bf16x8, b), acc[nt], 0,0,0);
        }
    }
    #pragma unroll
    for (int nt = 0; nt < 2; nt++){
        #pragma unroll
        for (int r = 0; r < 16; r++){
            int row = w*32 + (r&3) + 8*(r>>2) + 4*kh;
            int col = nt*32 + m;
            out[(r0 + row)*DCN + col] = acc[nt][r];
        }
    }
}

// ---------------------------------------------------------------------------
// Attention + lstm_in assembly. One block per g.
__global__ void __launch_bounds__(256)
k_attention(const float* __restrict__ gout, const float* __restrict__ cemb,
            const float* __restrict__ cid, const float* __restrict__ conc,
            const float* __restrict__ curres, float* __restrict__ lstm_in){
    int g = blockIdx.x; int tid = threadIdx.x;
    __shared__ float gg[NNODE*65];
    __shared__ float ce_s[CP1N];
    __shared__ float q_s[DCN];
    __shared__ float sc[256];
    __shared__ float red[256];
    __shared__ float part[4][DCN];
    __shared__ float oacc[DCN];
    __shared__ float num_s;
    if (tid < CP1N) ce_s[tid] = cemb[(size_t)g*CP1N + tid];
    if (tid < DCN) oacc[tid] = 0.f;
    for (int i = tid; i < NNODE*DCN; i += 256){
        int n = i >> 6, d = i & 63;
        gg[n*65 + d] = gout[((size_t)g*NNODE + n)*DCN + d];
    }
    red[tid] = (tid < CP1N) ? cid[(size_t)g*CP1N + tid] : 0.f;
    __syncthreads();
    for (int s = 128; s > 0; s >>= 1){ if (tid < s) red[tid] += red[tid+s]; __syncthreads(); }
    if (tid == 0){ float nm = red[0]; num_s = (nm == 0.f) ? 1.f : nm; }
    __syncthreads();
    for (int c = 0; c < CP1N; c++){
        float ce = ce_s[c];
        if (ce == 0.f) continue;          // uniform across block
        if (tid < DCN) q_s[tid] = ce * conc[c*DCN + tid];
        __syncthreads();
        float s = 0.f;
        if (tid < NNODE){
            const float* gr_ = &gg[tid*65];
            #pragma unroll 16
            for (int d = 0; d < DCN; d++) s += q_s[d] * gr_[d];
        }
        red[tid] = (tid < NNODE) ? s : -1e30f;
        __syncthreads();
        for (int t2 = 128; t2 > 0; t2 >>= 1){ if (tid < t2) red[tid] = fmaxf(red[tid], red[tid+t2]); __syncthreads(); }
        float mx = red[0];
        __syncthreads();
        float e = (tid < NNODE) ? expf(s - mx) : 0.f;
        sc[tid] = e;
        red[tid] = e;
        __syncthreads();
        for (int t2 = 128; t2 > 0; t2 >>= 1){ if (tid < t2) red[tid] += red[tid+t2]; __syncthreads(); }
        float inv = ce / red[0];
        int d = tid & 63, ngp = tid >> 6;
        float pa = 0.f;
        for (int n = ngp; n < NNODE; n += 4) pa += sc[n] * gg[n*65 + d];
        part[ngp][d] = pa;
        __syncthreads();
        if (tid < DCN) oacc[tid] += inv * (part[0][tid] + part[1][tid] + part[2][tid] + part[3][tid]);
        __syncthreads();
    }
    if (tid < FEATN){
        float v;
        if      (tid < CP1N)       v = ce_s[tid];
        else if (tid < CP1N+DCN)   v = oacc[tid-CP1N] / num_s;
        else                       v = curres[(size_t)g*2 + (tid-CP1N-DCN)];
        lstm_in[(size_t)g*FEATN + tid] = v;
    }
}

// ---------------------------------------------------------------------------
// gi_all = lstm_in @ Wih^T + (bih + bhh)    (800 x 1024, K=177)
__global__ void __launch_bounds__(256)
k_gi(const float* __restrict__ lstm_in, const float* __restrict__ wihT,
     const float* __restrict__ bih, const float* __restrict__ bhh, float* __restrict__ gi){
    int rb = blockIdx.x;   // 100 blocks of 8 rows
    int jb = blockIdx.y;   // 4
    int tid = threadIdx.x;
    __shared__ float in_s[8][FEATN];
    for (int i = tid; i < 8*FEATN; i += 256){ int r = i/FEATN, k = i%FEATN; in_s[r][k] = lstm_in[((size_t)rb*8+r)*FEATN + k]; }
    __syncthreads();
    int j = jb*256 + tid;
    float acc[8];
    #pragma unroll
    for (int i = 0; i < 8; i++) acc[i] = 0.f;
    for (int k = 0; k < FEATN; k++){
        float w = wihT[(size_t)k*1024 + j];
        #pragma unroll
        for (int i = 0; i < 8; i++) acc[i] += in_s[i][k] * w;
    }
    float b = bih[j] + bhh[j];
    #pragma unroll
    for (int i = 0; i < 8; i++) gi[((size_t)rb*8+i)*1024 + j] = acc[i] + b;
}

// ---------------------------------------------------------------------------
// Sequential LSTM: one block per batch item. Whh CU-resident:
// 96 bf16-pairs/thread in VGPRs + 32 pairs in LDS (128 KB). h broadcast via
// LDS u32 read (2/thread) + v_readlane -> SGPR-uniform operand for v_dot2_f32_bf16.
// __launch_bounds__(1024, 4): 4 waves/EU -> 128-VGPR cap so wreg[96] stays in
// registers (R4's default 64-VGPR cap spilled it to scratch: 335us vs ~130 predicted).
static const int WREG = 96;
static const int WLDS = 32;   // pairs WREG..127

__global__ void __launch_bounds__(1024, 4)
k_lstm(const float* __restrict__ gi, const unsigned* __restrict__ whhP, float* __restrict__ out){
    int b = blockIdx.x; int tid = threadIdx.x;
    __shared__ unsigned ldsw[WLDS][1024];    // 128 KB
    __shared__ float gates[1024];
    __shared__ __align__(8) u16 h16[HID];    // packed bf16 h, read as u32 pairs
    unsigned wreg[WREG];
    #pragma unroll
    for (int i = 0; i < WREG; i++) wreg[i] = whhP[(size_t)i*1024 + tid];
    #pragma unroll
    for (int i = 0; i < WLDS; i++) ldsw[i][tid] = whhP[(size_t)(WREG+i)*1024 + tid];
    if (tid < 128) ((unsigned*)h16)[tid] = 0u;
    float c_reg = 0.f;
    int lane = tid & 63;
    __syncthreads();
    float giv = gi[(size_t)b*SLN*1024 + tid];
    for (int t = 0; t < SLN; t++){
        unsigned hv0 = ((const unsigned*)h16)[lane];
        unsigned hv1 = ((const unsigned*)h16)[64 + lane];
        float acc = giv;
        if (t+1 < SLN) giv = gi[((size_t)b*SLN + t + 1)*1024 + tid];
        #pragma unroll
        for (int p = 0; p < 64; p++){
            unsigned hp = (unsigned)__builtin_amdgcn_readlane((int)hv0, p);
            acc = dot2bf(wreg[p], hp, acc);
        }
        #pragma unroll
        for (int p = 64; p < WREG; p++){
            unsigned hp = (unsigned)__builtin_amdgcn_readlane((int)hv1, p - 64);
            acc = dot2bf(wreg[p], hp, acc);
        }
        #pragma unroll
        for (int p = WREG; p < 128; p++){
            unsigned hp = (unsigned)__builtin_amdgcn_readlane((int)hv1, p - 64);
            acc = dot2bf(ldsw[p - WREG][tid], hp, acc);
        }
        gates[tid] = acc;
        __syncthreads();
        if (tid < HID){
            float i_ = sigf(gates[tid]);
            float f_ = sigf(gates[tid+256]);
            float g_ = tanhf(gates[tid+512]);
            float o_ = sigf(gates[tid+768]);
            c_reg = f_*c_reg + i_*g_;
            float h = o_*tanhf(c_reg);
            out[((size_t)b*SLN + t)*HID + tid] = h;
            h16[tid] = f2bf(h);
        }
        __syncthreads();
    }
}

// ---------------------------------------------------------------------------
// pred + masked BCE per row; outputs sigmoid(fp), ft; atomics for loss sums.
__global__ void __launch_bounds__(128)
k_final(const float* __restrict__ lstm_out, const float* __restrict__ pw, const float* __restrict__ pb,
        const float* __restrict__ tc, const float* __restrict__ result,
        float* __restrict__ out, float* __restrict__ lacc){
    int row = blockIdx.x; int tid = threadIdx.x;
    __shared__ __align__(16) float h_s[HID];
    __shared__ float redv[128], redn[128];
    h_s[tid]       = lstm_out[(size_t)row*HID + tid];
    h_s[tid + 128] = lstm_out[(size_t)row*HID + tid + 128];
    __syncthreads();
    float v = 0.f, n = 0.f;
    if (tid < CP1N){
        float acc = pb[tid];
        const float4* wr = (const float4*)(pw + (size_t)tid*HID);
        const float4* hp = (const float4*)h_s;
        #pragma unroll 8
        for (int k4 = 0; k4 < 64; k4++){
            float4 w = wr[k4]; float4 h4 = hp[k4];
            acc += h4.x*w.x + h4.y*w.y + h4.z*w.z + h4.w*w.w;
        }
        float t = tc[(size_t)row*CP1N + tid];
        v = acc*t; n = t;
    }
    redv[tid] = v; redn[tid] = n;
    __syncthreads();
    for (int s = 64; s > 0; s >>= 1){
        if (tid < s){ redv[tid] += redv[tid+s]; redn[tid] += redn[tid+s]; }
        __syncthreads();
    }
    if (tid == 0){
        float nc = redn[0];
        bool mask = nc > 0.f;
        float fp = redv[0] / (mask ? nc : 1.f);
        float ft = result[row];
        float bce = fmaxf(fp, 0.f) - fp*ft + log1pf(expf(-fabsf(fp)));
        out[1 + row]      = 1.f/(1.f + expf(-fp));
        out[1 + GN + row] = ft;
        if (mask){ atomicAdd(&lacc[0], bce); atomicAdd(&lacc[1], 1.f); }
    }
}

__global__ void k_loss_final(const float* __restrict__ lacc, float* __restrict__ out){
    out[0] = lacc[0] / fmaxf(lacc[1], 1.f);
}

// ---------------------------------------------------------------------------
extern "C" void kernel_launch(void* const* d_in, const int* in_sizes, int n_in,
                              void* d_out, int out_size, void* d_ws, size_t ws_size,
                              hipStream_t stream) {
    const float* c_id        = (const float*)d_in[1];
    const int*   node_id     = (const int*)  d_in[2];
    const int*   edge        = (const int*)  d_in[3];
    const int*   etype       = (const int*)  d_in[4];
    const float* target_c    = (const float*)d_in[5];
    const float* result      = (const float*)d_in[6];
    const float* c_embed     = (const float*)d_in[7];
    const float* cur_result  = (const float*)d_in[8];
    const float* node_emb_w  = (const float*)d_in[9];
    const float* edge_emb_w  = (const float*)d_in[10];
    const float* ggnn_w      = (const float*)d_in[11];
    const float* gru_w_ih    = (const float*)d_in[12];
    const float* gru_w_hh    = (const float*)d_in[13];
    const float* gru_b_ih    = (const float*)d_in[14];
    const float* gru_b_hh    = (const float*)d_in[15];
    const float* transdim_w  = (const float*)d_in[16];
    const float* concept     = (const float*)d_in[17];
    const float* lstm_w_ih   = (const float*)d_in[18];
    const float* lstm_w_hh   = (const float*)d_in[19];
    const float* lstm_b_ih   = (const float*)d_in[20];
    const float* lstm_b_hh   = (const float*)d_in[21];
    const float* pred_w      = (const float*)d_in[22];
    const float* pred_b      = (const float*)d_in[23];
    float* out = (float*)d_out;

    char* ws = (char*)d_ws;
    size_t off = 0;
    auto alloc = [&](size_t bytes) -> void* {
        void* p = ws + off;
        off += (bytes + 255) & ~(size_t)255;
        return p;
    };
    u16*      xb       = (u16*)     alloc((size_t)MROW*DIM*2);
    u16*      aggb     = (u16*)     alloc((size_t)MROW*DIM*2);
    int*      csr_src  = (int*)     alloc((size_t)GN*NEDGE*4);
    float*    csr_w    = (float*)   alloc((size_t)GN*NEDGE*4);
    int*      csr_off  = (int*)     alloc((size_t)GN*(NNODE+1)*4);
    float*    lstm_in  = (float*)   alloc((size_t)GN*FEATN*4);
    float*    gi       = (float*)   alloc((size_t)GN*1024*4);
    unsigned* whhP     = (unsigned*)alloc((size_t)128*1024*4);
    float*    wihT     = (float*)   alloc((size_t)FEATN*1024*4);
    float*    lstm_out = (float*)   alloc((size_t)GN*HID*4);
    u16*      wihb     = (u16*)     alloc((size_t)384*128*2);
    u16*      whhb     = (u16*)     alloc((size_t)384*128*2);
    u16*      gwTb     = (u16*)     alloc((size_t)4*128*128*2);
    u16*      twb      = (u16*)     alloc((size_t)DCN*DIM*2);
    float*    lacc     = (float*)   alloc(256);
    float*    ggnn_out = (float*)aggb;   // aggb (bf16, MROW*128*2 B) dead after layer 4; same byte size as MROW*64 fp32

    hipMemsetAsync(lacc, 0, 8, stream);
    {
        int total = 128*1024 + FEATN*1024;
        k_transpose_w<<<(total + 255)/256, 256, 0, stream>>>(lstm_w_hh, lstm_w_ih, whhP, wihT);
    }
    k_convert_w<<<672, 256, 0, stream>>>(gru_w_ih, gru_w_hh, ggnn_w, transdim_w, wihb, whhb, gwTb, twb);
    k_build_csr<<<GN, 256, 0, stream>>>(edge, etype, edge_emb_w, csr_src, csr_w, csr_off);
    k_gather_x<<<4096, 256, 0, stream>>>(node_id, (const float4*)node_emb_w, (u16x8*)xb);
    for (int l = 0; l < 4; l++){
        k_mm_scatter<<<GN, 256, 0, stream>>>(xb, gwTb + (size_t)l*DIM*DIM,
                                             csr_src, csr_w, csr_off, aggb);
        k_gru_mfma<<<MROW/64, 512, 0, stream>>>(xb, aggb, wihb, whhb, gru_b_ih, gru_b_hh);
    }
    k_transdim<<<MROW/128, 256, 0, stream>>>(xb, twb, ggnn_out);
    k_attention<<<GN, 256, 0, stream>>>(ggnn_out, c_embed, c_id, concept, cur_result, lstm_in);
    k_gi<<<dim3(100, 4), 256, 0, stream>>>(lstm_in, wihT, lstm_b_ih, lstm_b_hh, gi);
    k_lstm<<<BSZ, 1024, 0, stream>>>(gi, whhP, lstm_out);
    k_final<<<GN, 128, 0, stream>>>(lstm_out, pred_w, pred_b, target_c, result, out, lacc);
    k_loss_final<<<1, 1, 0, stream>>>(lacc, out);
}

// Round 6
// 1845.181 us; speedup vs baseline: 1.0492x; 1.0492x over previous
//
#include <hip/hip_runtime.h>
#include <math.h>

// Problem constants
static const int BSZ   = 8;
static const int SLN   = 100;
static const int NNODE = 200;
static const int NEDGE = 600;
static const int CP1N  = 111;
static const int DIM   = 128;
static const int DCN   = 64;
static const int HID   = 256;
static const int FEATN = 177;   // CP1N + DCN + 2
static const int GN    = 800;   // BS*SL
static const int MROW  = 160000; // GN*NNODE

typedef unsigned short u16;
typedef u16    u16x8  __attribute__((ext_vector_type(8)));
typedef __bf16 bf16x8 __attribute__((ext_vector_type(8)));
typedef __bf16 bf16x2 __attribute__((ext_vector_type(2)));
typedef float  f32x16 __attribute__((ext_vector_type(16)));

#if defined(__has_builtin)
# if __has_builtin(__builtin_amdgcn_fdot2_f32_bf16)
#  define HAVE_FDOT2 1
# else
#  define HAVE_FDOT2 0
# endif
#else
# define HAVE_FDOT2 0
#endif

__device__ __forceinline__ float sigf(float v){ return 1.0f/(1.0f + expf(-v)); }
__device__ __forceinline__ u16 f2bf(float f){
    union { float f; unsigned u; } v; v.f = f;
    unsigned r = v.u + 0x7FFFu + ((v.u >> 16) & 1u);
    return (u16)(r >> 16);
}
__device__ __forceinline__ float bf2f(u16 u){
    union { unsigned u; float f; } v; v.u = ((unsigned)u) << 16;
    return v.f;
}
__device__ __forceinline__ float dot2bf(unsigned w, unsigned h, float acc){
#if HAVE_FDOT2
    return __builtin_amdgcn_fdot2_f32_bf16(__builtin_bit_cast(bf16x2, w),
                                           __builtin_bit_cast(bf16x2, h), acc, false);
#else
    acc += bf2f((u16)(w & 0xffffu)) * bf2f((u16)(h & 0xffffu));
    acc += bf2f((u16)(w >> 16))     * bf2f((u16)(h >> 16));
    return acc;
#endif
}

// ---------------------------------------------------------------------------
// whhP[k2][j] = packed bf16 pair (Whh[j][2k2], Whh[j][2k2+1]);  WihT[k][j] = Wih[j][k] fp32
__global__ void k_transpose_w(const float* __restrict__ whh, const float* __restrict__ wih,
                              unsigned* __restrict__ whhP, float* __restrict__ wihT){
    int idx = blockIdx.x*blockDim.x + threadIdx.x;
    const int total1 = 128*1024;
    if (idx < total1){
        int k2 = idx >> 10, j = idx & 1023;
        u16 lo = f2bf(whh[(size_t)j*256 + 2*k2]);
        u16 hi = f2bf(whh[(size_t)j*256 + 2*k2 + 1]);
        whhP[(size_t)k2*1024 + j] = (unsigned)lo | ((unsigned)hi << 16);
    }
    int idx2 = idx - total1;
    const int total2 = FEATN*1024;
    if (idx2 >= 0 && idx2 < total2){
        int k = idx2 >> 10, j = idx2 & 1023;
        wihT[(size_t)k*1024 + j] = wih[(size_t)j*FEATN + k];
    }
}

// ---------------------------------------------------------------------------
// bf16 weight conversions: wih/whh (GRU, natural layout), gwT (transposed ggnn), tw (natural)
__global__ void k_convert_w(const float* __restrict__ wih, const float* __restrict__ whh,
                            const float* __restrict__ gw, const float* __restrict__ tw,
                            u16* __restrict__ wihb, u16* __restrict__ whhb,
                            u16* __restrict__ gwTb, u16* __restrict__ twb){
    int idx = blockIdx.x*blockDim.x + threadIdx.x;
    if (idx < 49152){
        wihb[idx] = f2bf(wih[idx]);
    } else if (idx < 98304){
        int t = idx - 49152;
        whhb[t] = f2bf(whh[t]);
    } else if (idx < 163840){
        int t = idx - 98304;
        int l = t >> 14, rem = t & 16383, n = rem >> 7, k = rem & 127;
        gwTb[t] = f2bf(gw[((size_t)l*128 + k)*128 + n]);
    } else if (idx < 172032){
        int t = idx - 163840;
        twb[t] = f2bf(tw[t]);
    }
}

// ---------------------------------------------------------------------------
// Per-graph CSR over dst + per-edge weight = mean(edge_embed_w[type])
__global__ void __launch_bounds__(256)
k_build_csr(const int* __restrict__ edge, const int* __restrict__ etype,
            const float* __restrict__ eembed,
            int* __restrict__ csr_src, float* __restrict__ csr_w, int* __restrict__ csr_off){
    int g = blockIdx.x; int tid = threadIdx.x;
    __shared__ float tmean[8];
    __shared__ float tpart[8][32];
    __shared__ int cnt[NNODE];
    __shared__ int offs[NNODE+1];
    __shared__ int cur[NNODE];
    {
        int ty = tid >> 5, lane = tid & 31;
        float s = 0.f;
        for (int i = lane; i < DIM; i += 32) s += eembed[ty*DIM + i];
        tpart[ty][lane] = s;
    }
    for (int i = tid; i < NNODE; i += 256) cnt[i] = 0;
    __syncthreads();
    if (tid < 8){
        float s = 0.f;
        for (int i = 0; i < 32; i++) s += tpart[tid][i];
        tmean[tid] = s / (float)DIM;
    }
    for (int e = tid; e < NEDGE; e += 256){
        int dst = edge[((size_t)g*2+1)*NEDGE + e];
        atomicAdd(&cnt[dst], 1);
    }
    __syncthreads();
    if (tid == 0){
        int run = 0;
        for (int i = 0; i < NNODE; i++){ offs[i] = run; run += cnt[i]; }
        offs[NNODE] = run;
    }
    __syncthreads();
    for (int i = tid; i < NNODE; i += 256) cur[i] = offs[i];
    for (int i = tid; i < NNODE+1; i += 256) csr_off[(size_t)g*(NNODE+1)+i] = offs[i];
    __syncthreads();
    for (int e = tid; e < NEDGE; e += 256){
        int dst = edge[((size_t)g*2+1)*NEDGE + e];
        int src = edge[((size_t)g*2+0)*NEDGE + e];
        float w = tmean[etype[(size_t)g*NEDGE + e]];
        int pos = atomicAdd(&cur[dst], 1);
        csr_src[(size_t)g*NEDGE + pos] = src;
        csr_w [(size_t)g*NEDGE + pos] = w;
    }
}

// ---------------------------------------------------------------------------
// xb = bf16(node_embed_w[node_id])
__global__ void k_gather_x(const int* __restrict__ nid, const float4* __restrict__ emb,
                           u16x8* __restrict__ xb){
    const long total = (long)MROW*16;   // 8-element chunks
    for (long c = (long)blockIdx.x*blockDim.x + threadIdx.x; c < total; c += (long)gridDim.x*blockDim.x){
        long row = c >> 4; int p = (int)(c & 15);
        float4 a = emb[(size_t)nid[row]*32 + p*2];
        float4 b = emb[(size_t)nid[row]*32 + p*2 + 1];
        u16x8 v;
        v[0]=f2bf(a.x); v[1]=f2bf(a.y); v[2]=f2bf(a.z); v[3]=f2bf(a.w);
        v[4]=f2bf(b.x); v[5]=f2bf(b.y); v[6]=f2bf(b.z); v[7]=f2bf(b.w);
        xb[c] = v;
    }
}

// ---------------------------------------------------------------------------
// MFMA m = x_g @ W (A-frags straight from global), m in LDS bf16, CSR scatter -> aggb
__global__ void __launch_bounds__(256)
k_mm_scatter(const u16* __restrict__ xb, const u16* __restrict__ gwTb_l,
             const int* __restrict__ csr_src, const float* __restrict__ csr_w,
             const int* __restrict__ csr_off, u16* __restrict__ aggb){
    __shared__ u16 m_s[224*128];       // bf16 m, 57344 B
    int g = blockIdx.x;
    int tid = threadIdx.x;
    const u16x8* xg = (const u16x8*)(xb + (size_t)g*NNODE*DIM);
    int w = tid >> 6, lane = tid & 63;
    int nbase = w*32;
    int m = lane & 31, kh = lane >> 5;
    f32x16 acc[7];
    #pragma unroll
    for (int t = 0; t < 7; t++) acc[t] = (f32x16)0.f;
    const u16x8* bp = (const u16x8*)gwTb_l;
    int nrow = nbase + m;
    #pragma unroll
    for (int kc = 0; kc < 8; kc++){
        u16x8 b = bp[nrow*16 + kc*2 + kh];
        #pragma unroll
        for (int mt = 0; mt < 7; mt++){
            int arow = mt*32 + m;
            u16x8 a = {};
            if (arow < NNODE) a = xg[arow*16 + kc*2 + kh];
            acc[mt] = __builtin_amdgcn_mfma_f32_32x32x16_bf16(
                __builtin_bit_cast(bf16x8, a), __builtin_bit_cast(bf16x8, b), acc[mt], 0, 0, 0);
        }
    }
    // Write m to LDS as bf16
    #pragma unroll
    for (int mt = 0; mt < 7; mt++){
        #pragma unroll
        for (int r = 0; r < 16; r++){
            int row = mt*32 + (r&3) + 8*(r>>2) + 4*kh;
            int col = nbase + m;
            m_s[row*128 + col] = f2bf(acc[mt][r]);
        }
    }
    __syncthreads();
    // CSR scatter: agg[n][j] = sum_p w[p] * m[src[p]][j]
    const int*   off  = csr_off + (size_t)g*(NNODE+1);
    const int*   srcp = csr_src + (size_t)g*NEDGE;
    const float* wp   = csr_w   + (size_t)g*NEDGE;
    int j = tid & 127, rg = tid >> 7;
    for (int i = 0; i < 100; i++){
        int n = rg*100 + i;
        int b = off[n], e = off[n+1];
        float a = 0.f;
        for (int p = b; p < e; p++) a += wp[p] * bf2f(m_s[srcp[p]*128 + j]);
        aggb[((size_t)g*NNODE + n)*DIM + j] = f2bf(a);
    }
}

// ---------------------------------------------------------------------------
// Fused MFMA GRU layer. Grid 2500 x 512 threads. M-tile 64 rows. State is bf16 xb.
__global__ void __launch_bounds__(512)
k_gru_mfma(u16* __restrict__ xb, const u16* __restrict__ aggb,
           const u16* __restrict__ wihb, const u16* __restrict__ whhb,
           const float* __restrict__ bih, const float* __restrict__ bhh){
    __shared__ u16x8 afragA[1024];   // agg fragments [mtile2][kc8][lane64]
    __shared__ u16x8 afragX[1024];   // x fragments
    int tid = threadIdx.x;
    long r0 = (long)blockIdx.x * 64;
    // Stage A fragments
    const u16x8* aggp = (const u16x8*)aggb;
    const u16x8* xbp  = (const u16x8*)xb;
    for (int c = tid; c < 2048; c += 512){
        int mat = c >> 10, cc = c & 1023;
        int row = cc >> 4, kc8 = cc & 15;
        u16x8 v = (mat ? xbp : aggp)[(r0 + row)*16 + kc8];
        int slot = ((row>>5)*8 + (kc8>>1))*64 + (row&31) + 32*(kc8&1);
        (mat ? afragX : afragA)[slot] = v;
    }
    __syncthreads();
    int w = tid >> 6, lane = tid & 63;
    int mt = w >> 2;               // 0..1
    int cb = (w & 3) * 32;         // col base within 128
    f32x16 acc[6];
    #pragma unroll
    for (int t = 0; t < 6; t++) acc[t] = (f32x16)0.f;
    const u16x8* bi = (const u16x8*)wihb;
    const u16x8* bh = (const u16x8*)whhb;
    int kh = lane >> 5;
    int ncol = cb + (lane & 31);
    #pragma unroll
    for (int kc = 0; kc < 8; kc++){
        u16x8 aA = afragA[(mt*8 + kc)*64 + lane];
        u16x8 aX = afragX[(mt*8 + kc)*64 + lane];
        #pragma unroll
        for (int g3 = 0; g3 < 3; g3++){
            int n = g3*128 + ncol;
            u16x8 b1 = bi[n*16 + kc*2 + kh];
            u16x8 b2 = bh[n*16 + kc*2 + kh];
            acc[g3]   = __builtin_amdgcn_mfma_f32_32x32x16_bf16(
                __builtin_bit_cast(bf16x8, aA), __builtin_bit_cast(bf16x8, b1), acc[g3], 0,0,0);
            acc[3+g3] = __builtin_amdgcn_mfma_f32_32x32x16_bf16(
                __builtin_bit_cast(bf16x8, aX), __builtin_bit_cast(bf16x8, b2), acc[3+g3], 0,0,0);
        }
    }
    // GRU elementwise in fp32 from bf16 inputs
    int col = cb + (lane & 31);
    float bir = bih[col], biz = bih[col+128], bin = bih[col+256];
    float bhr = bhh[col], bhz = bhh[col+128], bhn = bhh[col+256];
    #pragma unroll
    for (int r = 0; r < 16; r++){
        int row = mt*32 + (r&3) + 8*(r>>2) + 4*kh;
        size_t gi_ = (size_t)(r0 + row)*DIM + col;
        float xo = bf2f(xb[gi_]);
        float rr  = sigf(acc[0][r] + bir + acc[3][r] + bhr);
        float zz  = sigf(acc[1][r] + biz + acc[4][r] + bhz);
        float nn_ = tanhf(acc[2][r] + bin + rr*(acc[5][r] + bhn));
        float xn  = (1.f - zz)*nn_ + zz*xo;
        xb[gi_]  = f2bf(xn);
    }
}

// ---------------------------------------------------------------------------
// ggnn_out = x @ transdim_w^T via MFMA (M x 64 fp32 out, K=128). Grid 1250 x 256.
__global__ void __launch_bounds__(256)
k_transdim(const u16* __restrict__ xb, const u16* __restrict__ twb, float* __restrict__ out){
    int tid = threadIdx.x;
    int w = tid >> 6, lane = tid & 63;
    int m = lane & 31, kh = lane >> 5;
    long r0 = (long)blockIdx.x * 128;
    const u16x8* xp = (const u16x8*)xb;
    const u16x8* tp = (const u16x8*)twb;
    long rowA = r0 + w*32 + m;
    f32x16 acc[2];
    acc[0] = (f32x16)0.f; acc[1] = (f32x16)0.f;
    #pragma unroll
    for (int kc = 0; kc < 8; kc++){
        u16x8 a = xp[rowA*16 + kc*2 + kh];
        #pragma unroll
        for (int nt = 0; nt < 2; nt++){
            u16x8 b = tp[(nt*32 + m)*16 + kc*2 + kh];
            acc[nt] = __builtin_amdgcn_mfma_f32_32x32x16_bf16(
                __builtin_bit_cast(bf16x8, a), __builtin_bit_cast(bf16x8, b), acc[nt], 0,0,0);
        }
    }
    #pragma unroll
    for (int nt = 0; nt < 2; nt++){
        #pragma unroll
        for (int r = 0; r < 16; r++){
            int row = w*32 + (r&3) + 8*(r>>2) + 4*kh;
            int col = nt*32 + m;
            out[(r0 + row)*DCN + col] = acc[nt][r];
        }
    }
}

// ---------------------------------------------------------------------------
// Attention + lstm_in assembly. One block per g.
__global__ void __launch_bounds__(256)
k_attention(const float* __restrict__ gout, const float* __restrict__ cemb,
            const float* __restrict__ cid, const float* __restrict__ conc,
            const float* __restrict__ curres, float* __restrict__ lstm_in){
    int g = blockIdx.x; int tid = threadIdx.x;
    __shared__ float gg[NNODE*65];
    __shared__ float ce_s[CP1N];
    __shared__ float q_s[DCN];
    __shared__ float sc[256];
    __shared__ float red[256];
    __shared__ float part[4][DCN];
    __shared__ float oacc[DCN];
    __shared__ float num_s;
    if (tid < CP1N) ce_s[tid] = cemb[(size_t)g*CP1N + tid];
    if (tid < DCN) oacc[tid] = 0.f;
    for (int i = tid; i < NNODE*DCN; i += 256){
        int n = i >> 6, d = i & 63;
        gg[n*65 + d] = gout[((size_t)g*NNODE + n)*DCN + d];
    }
    red[tid] = (tid < CP1N) ? cid[(size_t)g*CP1N + tid] : 0.f;
    __syncthreads();
    for (int s = 128; s > 0; s >>= 1){ if (tid < s) red[tid] += red[tid+s]; __syncthreads(); }
    if (tid == 0){ float nm = red[0]; num_s = (nm == 0.f) ? 1.f : nm; }
    __syncthreads();
    for (int c = 0; c < CP1N; c++){
        float ce = ce_s[c];
        if (ce == 0.f) continue;          // uniform across block
        if (tid < DCN) q_s[tid] = ce * conc[c*DCN + tid];
        __syncthreads();
        float s = 0.f;
        if (tid < NNODE){
            const float* gr_ = &gg[tid*65];
            #pragma unroll 16
            for (int d = 0; d < DCN; d++) s += q_s[d] * gr_[d];
        }
        red[tid] = (tid < NNODE) ? s : -1e30f;
        __syncthreads();
        for (int t2 = 128; t2 > 0; t2 >>= 1){ if (tid < t2) red[tid] = fmaxf(red[tid], red[tid+t2]); __syncthreads(); }
        float mx = red[0];
        __syncthreads();
        float e = (tid < NNODE) ? expf(s - mx) : 0.f;
        sc[tid] = e;
        red[tid] = e;
        __syncthreads();
        for (int t2 = 128; t2 > 0; t2 >>= 1){ if (tid < t2) red[tid] += red[tid+t2]; __syncthreads(); }
        float inv = ce / red[0];
        int d = tid & 63, ngp = tid >> 6;
        float pa = 0.f;
        for (int n = ngp; n < NNODE; n += 4) pa += sc[n] * gg[n*65 + d];
        part[ngp][d] = pa;
        __syncthreads();
        if (tid < DCN) oacc[tid] += inv * (part[0][tid] + part[1][tid] + part[2][tid] + part[3][tid]);
        __syncthreads();
    }
    if (tid < FEATN){
        float v;
        if      (tid < CP1N)       v = ce_s[tid];
        else if (tid < CP1N+DCN)   v = oacc[tid-CP1N] / num_s;
        else                       v = curres[(size_t)g*2 + (tid-CP1N-DCN)];
        lstm_in[(size_t)g*FEATN + tid] = v;
    }
}

// ---------------------------------------------------------------------------
// gi_all = lstm_in @ Wih^T + (bih + bhh)    (800 x 1024, K=177)
__global__ void __launch_bounds__(256)
k_gi(const float* __restrict__ lstm_in, const float* __restrict__ wihT,
     const float* __restrict__ bih, const float* __restrict__ bhh, float* __restrict__ gi){
    int rb = blockIdx.x;   // 100 blocks of 8 rows
    int jb = blockIdx.y;   // 4
    int tid = threadIdx.x;
    __shared__ float in_s[8][FEATN];
    for (int i = tid; i < 8*FEATN; i += 256){ int r = i/FEATN, k = i%FEATN; in_s[r][k] = lstm_in[((size_t)rb*8+r)*FEATN + k]; }
    __syncthreads();
    int j = jb*256 + tid;
    float acc[8];
    #pragma unroll
    for (int i = 0; i < 8; i++) acc[i] = 0.f;
    for (int k = 0; k < FEATN; k++){
        float w = wihT[(size_t)k*1024 + j];
        #pragma unroll
        for (int i = 0; i < 8; i++) acc[i] += in_s[i][k] * w;
    }
    float b = bih[j] + bhh[j];
    #pragma unroll
    for (int i = 0; i < 8; i++) gi[((size_t)rb*8+i)*1024 + j] = acc[i] + b;
}

// ---------------------------------------------------------------------------
// Sequential LSTM: one block per batch item. Whh CU-resident:
// 104 bf16-pairs/thread in VGPRs + 24 pairs in LDS packed as uint4 (6 ds_read_b128
// per thread per step instead of 32 ds_read_b32 -> LDS pipe off the critical path).
// amdgpu_waves_per_eu(4,4) pins the allocator at 4 waves/EU = 128-reg budget.
static const int WREG = 104;
static const int WL4  = 6;    // 24 pairs = 6 uint4 groups (pairs 104..127)

__global__ void __launch_bounds__(1024)
__attribute__((amdgpu_waves_per_eu(4,4)))
k_lstm(const float* __restrict__ gi, const unsigned* __restrict__ whhP, float* __restrict__ out){
    int b = blockIdx.x; int tid = threadIdx.x;
    __shared__ uint4 ldsw4[WL4][1024];       // 96 KB
    __shared__ float gates[1024];
    __shared__ __align__(8) u16 h16[HID];    // packed bf16 h, read as u32 pairs
    unsigned wreg[WREG];
    #pragma unroll
    for (int i = 0; i < WREG; i++) wreg[i] = whhP[(size_t)i*1024 + tid];
    #pragma unroll
    for (int q = 0; q < WL4; q++){
        uint4 v;
        v.x = whhP[(size_t)(WREG + 4*q + 0)*1024 + tid];
        v.y = whhP[(size_t)(WREG + 4*q + 1)*1024 + tid];
        v.z = whhP[(size_t)(WREG + 4*q + 2)*1024 + tid];
        v.w = whhP[(size_t)(WREG + 4*q + 3)*1024 + tid];
        ldsw4[q][tid] = v;
    }
    if (tid < 128) ((unsigned*)h16)[tid] = 0u;
    float c_reg = 0.f;
    int lane = tid & 63;
    __syncthreads();
    float giv = gi[(size_t)b*SLN*1024 + tid];
    for (int t = 0; t < SLN; t++){
        unsigned hv0 = ((const unsigned*)h16)[lane];
        unsigned hv1 = ((const unsigned*)h16)[64 + lane];
        float acc0 = giv, acc1 = 0.f;
        if (t+1 < SLN) giv = gi[((size_t)b*SLN + t + 1)*1024 + tid];
        #pragma unroll
        for (int p = 0; p < 64; p += 2){
            unsigned hpa = (unsigned)__builtin_amdgcn_readlane((int)hv0, p);
            unsigned hpb = (unsigned)__builtin_amdgcn_readlane((int)hv0, p+1);
            acc0 = dot2bf(wreg[p],   hpa, acc0);
            acc1 = dot2bf(wreg[p+1], hpb, acc1);
        }
        #pragma unroll
        for (int p = 64; p < WREG; p += 2){
            unsigned hpa = (unsigned)__builtin_amdgcn_readlane((int)hv1, p - 64);
            unsigned hpb = (unsigned)__builtin_amdgcn_readlane((int)hv1, p - 63);
            acc0 = dot2bf(wreg[p],   hpa, acc0);
            acc1 = dot2bf(wreg[p+1], hpb, acc1);
        }
        #pragma unroll
        for (int q = 0; q < WL4; q++){
            uint4 wv = ldsw4[q][tid];
            int base = WREG + 4*q - 64;
            unsigned h0 = (unsigned)__builtin_amdgcn_readlane((int)hv1, base + 0);
            unsigned h1 = (unsigned)__builtin_amdgcn_readlane((int)hv1, base + 1);
            unsigned h2 = (unsigned)__builtin_amdgcn_readlane((int)hv1, base + 2);
            unsigned h3 = (unsigned)__builtin_amdgcn_readlane((int)hv1, base + 3);
            acc0 = dot2bf(wv.x, h0, acc0);
            acc1 = dot2bf(wv.y, h1, acc1);
            acc0 = dot2bf(wv.z, h2, acc0);
            acc1 = dot2bf(wv.w, h3, acc1);
        }
        gates[tid] = acc0 + acc1;
        __syncthreads();
        if (tid < HID){
            float i_ = sigf(gates[tid]);
            float f_ = sigf(gates[tid+256]);
            float g_ = tanhf(gates[tid+512]);
            float o_ = sigf(gates[tid+768]);
            c_reg = f_*c_reg + i_*g_;
            float h = o_*tanhf(c_reg);
            out[((size_t)b*SLN + t)*HID + tid] = h;
            h16[tid] = f2bf(h);
        }
        __syncthreads();
    }
}

// ---------------------------------------------------------------------------
// pred + masked BCE per row; outputs sigmoid(fp), ft; atomics for loss sums.
__global__ void __launch_bounds__(128)
k_final(const float* __restrict__ lstm_out, const float* __restrict__ pw, const float* __restrict__ pb,
        const float* __restrict__ tc, const float* __restrict__ result,
        float* __restrict__ out, float* __restrict__ lacc){
    int row = blockIdx.x; int tid = threadIdx.x;
    __shared__ __align__(16) float h_s[HID];
    __shared__ float redv[128], redn[128];
    h_s[tid]       = lstm_out[(size_t)row*HID + tid];
    h_s[tid + 128] = lstm_out[(size_t)row*HID + tid + 128];
    __syncthreads();
    float v = 0.f, n = 0.f;
    if (tid < CP1N){
        float acc = pb[tid];
        const float4* wr = (const float4*)(pw + (size_t)tid*HID);
        const float4* hp = (const float4*)h_s;
        #pragma unroll 8
        for (int k4 = 0; k4 < 64; k4++){
            float4 w = wr[k4]; float4 h4 = hp[k4];
            acc += h4.x*w.x + h4.y*w.y + h4.z*w.z + h4.w*w.w;
        }
        float t = tc[(size_t)row*CP1N + tid];
        v = acc*t; n = t;
    }
    redv[tid] = v; redn[tid] = n;
    __syncthreads();
    for (int s = 64; s > 0; s >>= 1){
        if (tid < s){ redv[tid] += redv[tid+s]; redn[tid] += redn[tid+s]; }
        __syncthreads();
    }
    if (tid == 0){
        float nc = redn[0];
        bool mask = nc > 0.f;
        float fp = redv[0] / (mask ? nc : 1.f);
        float ft = result[row];
        float bce = fmaxf(fp, 0.f) - fp*ft + log1pf(expf(-fabsf(fp)));
        out[1 + row]      = 1.f/(1.f + expf(-fp));
        out[1 + GN + row] = ft;
        if (mask){ atomicAdd(&lacc[0], bce); atomicAdd(&lacc[1], 1.f); }
    }
}

__global__ void k_loss_final(const float* __restrict__ lacc, float* __restrict__ out){
    out[0] = lacc[0] / fmaxf(lacc[1], 1.f);
}

// ---------------------------------------------------------------------------
extern "C" void kernel_launch(void* const* d_in, const int* in_sizes, int n_in,
                              void* d_out, int out_size, void* d_ws, size_t ws_size,
                              hipStream_t stream) {
    const float* c_id        = (const float*)d_in[1];
    const int*   node_id     = (const int*)  d_in[2];
    const int*   edge        = (const int*)  d_in[3];
    const int*   etype       = (const int*)  d_in[4];
    const float* target_c    = (const float*)d_in[5];
    const float* result      = (const float*)d_in[6];
    const float* c_embed     = (const float*)d_in[7];
    const float* cur_result  = (const float*)d_in[8];
    const float* node_emb_w  = (const float*)d_in[9];
    const float* edge_emb_w  = (const float*)d_in[10];
    const float* ggnn_w      = (const float*)d_in[11];
    const float* gru_w_ih    = (const float*)d_in[12];
    const float* gru_w_hh    = (const float*)d_in[13];
    const float* gru_b_ih    = (const float*)d_in[14];
    const float* gru_b_hh    = (const float*)d_in[15];
    const float* transdim_w  = (const float*)d_in[16];
    const float* concept     = (const float*)d_in[17];
    const float* lstm_w_ih   = (const float*)d_in[18];
    const float* lstm_w_hh   = (const float*)d_in[19];
    const float* lstm_b_ih   = (const float*)d_in[20];
    const float* lstm_b_hh   = (const float*)d_in[21];
    const float* pred_w      = (const float*)d_in[22];
    const float* pred_b      = (const float*)d_in[23];
    float* out = (float*)d_out;

    char* ws = (char*)d_ws;
    size_t off = 0;
    auto alloc = [&](size_t bytes) -> void* {
        void* p = ws + off;
        off += (bytes + 255) & ~(size_t)255;
        return p;
    };
    u16*      xb       = (u16*)     alloc((size_t)MROW*DIM*2);
    u16*      aggb     = (u16*)     alloc((size_t)MROW*DIM*2);
    int*      csr_src  = (int*)     alloc((size_t)GN*NEDGE*4);
    float*    csr_w    = (float*)   alloc((size_t)GN*NEDGE*4);
    int*      csr_off  = (int*)     alloc((size_t)GN*(NNODE+1)*4);
    float*    lstm_in  = (float*)   alloc((size_t)GN*FEATN*4);
    float*    gi       = (float*)   alloc((size_t)GN*1024*4);
    unsigned* whhP     = (unsigned*)alloc((size_t)128*1024*4);
    float*    wihT     = (float*)   alloc((size_t)FEATN*1024*4);
    float*    lstm_out = (float*)   alloc((size_t)GN*HID*4);
    u16*      wihb     = (u16*)     alloc((size_t)384*128*2);
    u16*      whhb     = (u16*)     alloc((size_t)384*128*2);
    u16*      gwTb     = (u16*)     alloc((size_t)4*128*128*2);
    u16*      twb      = (u16*)     alloc((size_t)DCN*DIM*2);
    float*    lacc     = (float*)   alloc(256);
    float*    ggnn_out = (float*)aggb;   // aggb (bf16, MROW*128*2 B) dead after layer 4; same byte size as MROW*64 fp32

    hipMemsetAsync(lacc, 0, 8, stream);
    {
        int total = 128*1024 + FEATN*1024;
        k_transpose_w<<<(total + 255)/256, 256, 0, stream>>>(lstm_w_hh, lstm_w_ih, whhP, wihT);
    }
    k_convert_w<<<672, 256, 0, stream>>>(gru_w_ih, gru_w_hh, ggnn_w, transdim_w, wihb, whhb, gwTb, twb);
    k_build_csr<<<GN, 256, 0, stream>>>(edge, etype, edge_emb_w, csr_src, csr_w, csr_off);
    k_gather_x<<<4096, 256, 0, stream>>>(node_id, (const float4*)node_emb_w, (u16x8*)xb);
    for (int l = 0; l < 4; l++){
        k_mm_scatter<<<GN, 256, 0, stream>>>(xb, gwTb + (size_t)l*DIM*DIM,
                                             csr_src, csr_w, csr_off, aggb);
        k_gru_mfma<<<MROW/64, 512, 0, stream>>>(xb, aggb, wihb, whhb, gru_b_ih, gru_b_hh);
    }
    k_transdim<<<MROW/128, 256, 0, stream>>>(xb, twb, ggnn_out);
    k_attention<<<GN, 256, 0, stream>>>(ggnn_out, c_embed, c_id, concept, cur_result, lstm_in);
    k_gi<<<dim3(100, 4), 256, 0, stream>>>(lstm_in, wihT, lstm_b_ih, lstm_b_hh, gi);
    k_lstm<<<BSZ, 1024, 0, stream>>>(gi, whhP, lstm_out);
    k_final<<<GN, 128, 0, stream>>>(lstm_out, pred_w, pred_b, target_c, result, out, lacc);
    k_loss_final<<<1, 1, 0, stream>>>(lacc, out);
}

// Round 7
// 1322.705 us; speedup vs baseline: 1.4636x; 1.3950x over previous
//
#include <hip/hip_runtime.h>
#include <math.h>

// Problem constants
static const int BSZ   = 8;
static const int SLN   = 100;
static const int NNODE = 200;
static const int NEDGE = 600;
static const int CP1N  = 111;
static const int DIM   = 128;
static const int DCN   = 64;
static const int HID   = 256;
static const int FEATN = 177;   // CP1N + DCN + 2
static const int GN    = 800;   // BS*SL
static const int MROW  = 160000; // GN*NNODE

typedef unsigned short u16;
typedef u16    u16x8  __attribute__((ext_vector_type(8)));
typedef __bf16 bf16x8 __attribute__((ext_vector_type(8)));
typedef __bf16 bf16x2 __attribute__((ext_vector_type(2)));
typedef float  f32x16 __attribute__((ext_vector_type(16)));

#if defined(__has_builtin)
# if __has_builtin(__builtin_amdgcn_fdot2_f32_bf16)
#  define HAVE_FDOT2 1
# else
#  define HAVE_FDOT2 0
# endif
#else
# define HAVE_FDOT2 0
#endif

__device__ __forceinline__ float sigf(float v){ return 1.0f/(1.0f + expf(-v)); }
__device__ __forceinline__ u16 f2bf(float f){
    union { float f; unsigned u; } v; v.f = f;
    unsigned r = v.u + 0x7FFFu + ((v.u >> 16) & 1u);
    return (u16)(r >> 16);
}
__device__ __forceinline__ float bf2f(u16 u){
    union { unsigned u; float f; } v; v.u = ((unsigned)u) << 16;
    return v.f;
}
__device__ __forceinline__ float dot2bf(unsigned w, unsigned h, float acc){
#if HAVE_FDOT2
    return __builtin_amdgcn_fdot2_f32_bf16(__builtin_bit_cast(bf16x2, w),
                                           __builtin_bit_cast(bf16x2, h), acc, false);
#else
    acc += bf2f((u16)(w & 0xffffu)) * bf2f((u16)(h & 0xffffu));
    acc += bf2f((u16)(w >> 16))     * bf2f((u16)(h >> 16));
    return acc;
#endif
}

// ---------------------------------------------------------------------------
// whhP[k2][j] = packed bf16 pair (Whh[j][2k2], Whh[j][2k2+1]);  WihT[k][j] = Wih[j][k] fp32
__global__ void k_transpose_w(const float* __restrict__ whh, const float* __restrict__ wih,
                              unsigned* __restrict__ whhP, float* __restrict__ wihT){
    int idx = blockIdx.x*blockDim.x + threadIdx.x;
    const int total1 = 128*1024;
    if (idx < total1){
        int k2 = idx >> 10, j = idx & 1023;
        u16 lo = f2bf(whh[(size_t)j*256 + 2*k2]);
        u16 hi = f2bf(whh[(size_t)j*256 + 2*k2 + 1]);
        whhP[(size_t)k2*1024 + j] = (unsigned)lo | ((unsigned)hi << 16);
    }
    int idx2 = idx - total1;
    const int total2 = FEATN*1024;
    if (idx2 >= 0 && idx2 < total2){
        int k = idx2 >> 10, j = idx2 & 1023;
        wihT[(size_t)k*1024 + j] = wih[(size_t)j*FEATN + k];
    }
}

// ---------------------------------------------------------------------------
// bf16 weight conversions: wih/whh (GRU, natural layout), gwT (transposed ggnn), tw (natural)
__global__ void k_convert_w(const float* __restrict__ wih, const float* __restrict__ whh,
                            const float* __restrict__ gw, const float* __restrict__ tw,
                            u16* __restrict__ wihb, u16* __restrict__ whhb,
                            u16* __restrict__ gwTb, u16* __restrict__ twb){
    int idx = blockIdx.x*blockDim.x + threadIdx.x;
    if (idx < 49152){
        wihb[idx] = f2bf(wih[idx]);
    } else if (idx < 98304){
        int t = idx - 49152;
        whhb[t] = f2bf(whh[t]);
    } else if (idx < 163840){
        int t = idx - 98304;
        int l = t >> 14, rem = t & 16383, n = rem >> 7, k = rem & 127;
        gwTb[t] = f2bf(gw[((size_t)l*128 + k)*128 + n]);
    } else if (idx < 172032){
        int t = idx - 163840;
        twb[t] = f2bf(tw[t]);
    }
}

// ---------------------------------------------------------------------------
// Per-graph CSR over dst + per-edge weight = mean(edge_embed_w[type])
__global__ void __launch_bounds__(256)
k_build_csr(const int* __restrict__ edge, const int* __restrict__ etype,
            const float* __restrict__ eembed,
            int* __restrict__ csr_src, float* __restrict__ csr_w, int* __restrict__ csr_off){
    int g = blockIdx.x; int tid = threadIdx.x;
    __shared__ float tmean[8];
    __shared__ float tpart[8][32];
    __shared__ int cnt[NNODE];
    __shared__ int offs[NNODE+1];
    __shared__ int cur[NNODE];
    {
        int ty = tid >> 5, lane = tid & 31;
        float s = 0.f;
        for (int i = lane; i < DIM; i += 32) s += eembed[ty*DIM + i];
        tpart[ty][lane] = s;
    }
    for (int i = tid; i < NNODE; i += 256) cnt[i] = 0;
    __syncthreads();
    if (tid < 8){
        float s = 0.f;
        for (int i = 0; i < 32; i++) s += tpart[tid][i];
        tmean[tid] = s / (float)DIM;
    }
    for (int e = tid; e < NEDGE; e += 256){
        int dst = edge[((size_t)g*2+1)*NEDGE + e];
        atomicAdd(&cnt[dst], 1);
    }
    __syncthreads();
    if (tid == 0){
        int run = 0;
        for (int i = 0; i < NNODE; i++){ offs[i] = run; run += cnt[i]; }
        offs[NNODE] = run;
    }
    __syncthreads();
    for (int i = tid; i < NNODE; i += 256) cur[i] = offs[i];
    for (int i = tid; i < NNODE+1; i += 256) csr_off[(size_t)g*(NNODE+1)+i] = offs[i];
    __syncthreads();
    for (int e = tid; e < NEDGE; e += 256){
        int dst = edge[((size_t)g*2+1)*NEDGE + e];
        int src = edge[((size_t)g*2+0)*NEDGE + e];
        float w = tmean[etype[(size_t)g*NEDGE + e]];
        int pos = atomicAdd(&cur[dst], 1);
        csr_src[(size_t)g*NEDGE + pos] = src;
        csr_w [(size_t)g*NEDGE + pos] = w;
    }
}

// ---------------------------------------------------------------------------
// xb = bf16(node_embed_w[node_id])
__global__ void k_gather_x(const int* __restrict__ nid, const float4* __restrict__ emb,
                           u16x8* __restrict__ xb){
    const long total = (long)MROW*16;   // 8-element chunks
    for (long c = (long)blockIdx.x*blockDim.x + threadIdx.x; c < total; c += (long)gridDim.x*blockDim.x){
        long row = c >> 4; int p = (int)(c & 15);
        float4 a = emb[(size_t)nid[row]*32 + p*2];
        float4 b = emb[(size_t)nid[row]*32 + p*2 + 1];
        u16x8 v;
        v[0]=f2bf(a.x); v[1]=f2bf(a.y); v[2]=f2bf(a.z); v[3]=f2bf(a.w);
        v[4]=f2bf(b.x); v[5]=f2bf(b.y); v[6]=f2bf(b.z); v[7]=f2bf(b.w);
        xb[c] = v;
    }
}

// ---------------------------------------------------------------------------
// MFMA m = x_g @ W with A staged coalesced in LDS (fragment order), then m
// overwrites the SAME LDS buffer (57 KB total -> 2 blocks/CU), then CSR
// scatter with 2-col-per-u32 LDS reads. One block per graph.
__global__ void __launch_bounds__(256)
k_mm_scatter(const u16* __restrict__ xb, const u16* __restrict__ gwTb_l,
             const int* __restrict__ csr_src, const float* __restrict__ csr_w,
             const int* __restrict__ csr_off, u16* __restrict__ aggb){
    __shared__ u16 smem[224*128];      // 57344 B: A-frags, later m (bf16)
    __shared__ int   e_src[NEDGE];
    __shared__ float e_w[NEDGE];
    __shared__ int   offs_s[NNODE+1];
    int g = blockIdx.x;
    int tid = threadIdx.x;
    const u16x8* xg = (const u16x8*)(xb + (size_t)g*NNODE*DIM);
    u16x8* afrag = (u16x8*)smem;       // 3584 slots: [tile7][kc8][lane64]
    // Stage A fragments coalesced (rows 200..223 zero)
    for (int c = tid; c < 3584; c += 256){
        int row = c >> 4, kc8 = c & 15;
        u16x8 v = {};
        if (row < NNODE) v = xg[row*16 + kc8];
        afrag[((row>>5)*8 + (kc8>>1))*64 + (row&31) + 32*(kc8&1)] = v;
    }
    // Stage CSR
    {
        const int*   srcp = csr_src + (size_t)g*NEDGE;
        const float* wp   = csr_w   + (size_t)g*NEDGE;
        const int*   off  = csr_off + (size_t)g*(NNODE+1);
        for (int i = tid; i < NEDGE; i += 256){ e_src[i] = srcp[i]; e_w[i] = wp[i]; }
        for (int i = tid; i <= NNODE; i += 256) offs_s[i] = off[i];
    }
    __syncthreads();
    int w = tid >> 6, lane = tid & 63;
    int nbase = w*32;
    int m = lane & 31, kh = lane >> 5;
    f32x16 acc[7];
    #pragma unroll
    for (int t = 0; t < 7; t++) acc[t] = (f32x16)0.f;
    const u16x8* bp = (const u16x8*)gwTb_l;
    int nrow = nbase + m;
    #pragma unroll
    for (int kc = 0; kc < 8; kc++){
        u16x8 b = bp[nrow*16 + kc*2 + kh];
        #pragma unroll
        for (int mt = 0; mt < 7; mt++){
            u16x8 a = afrag[(mt*8 + kc)*64 + lane];
            acc[mt] = __builtin_amdgcn_mfma_f32_32x32x16_bf16(
                __builtin_bit_cast(bf16x8, a), __builtin_bit_cast(bf16x8, b), acc[mt], 0, 0, 0);
        }
    }
    __syncthreads();   // all afrag reads complete before overwrite
    // Write m into the same LDS as bf16 [row][col]
    #pragma unroll
    for (int mt = 0; mt < 7; mt++){
        #pragma unroll
        for (int r = 0; r < 16; r++){
            int row = mt*32 + (r&3) + 8*(r>>2) + 4*kh;
            int col = nbase + m;
            smem[row*128 + col] = f2bf(acc[mt][r]);
        }
    }
    __syncthreads();
    // CSR scatter: thread handles 2 adjacent cols via u32 reads. 4 row groups x 50.
    const unsigned* m32 = (const unsigned*)smem;
    int j2 = tid & 63, rg = tid >> 6;
    unsigned* aggout = (unsigned*)(aggb + (size_t)g*NNODE*DIM);
    for (int i = 0; i < 50; i++){
        int n = rg*50 + i;
        int b0 = offs_s[n], e0 = offs_s[n+1];
        float a0 = 0.f, a1 = 0.f;
        for (int p = b0; p < e0; p++){
            unsigned mv = m32[e_src[p]*64 + j2];
            float w_ = e_w[p];
            a0 += w_ * bf2f((u16)(mv & 0xffffu));
            a1 += w_ * bf2f((u16)(mv >> 16));
        }
        aggout[(size_t)n*64 + j2] = (unsigned)f2bf(a0) | ((unsigned)f2bf(a1) << 16);
    }
}

// ---------------------------------------------------------------------------
// Fused MFMA GRU layer, M-tile 128. Grid 1250 x 512 threads.
// Wave w: row-group mtg=w>>2 (2 mtiles of 32), col-slice cb=(w&3)*32; computes
// all 6 gate blocks for 64 rows -> 12 MFMAs per kc vs 6 B-loads (2x density of
// the 64-tile version). Epilogue reads old x from the staged LDS fragments.
__global__ void __launch_bounds__(512, 2)
k_gru_mfma(u16* __restrict__ xb, const u16* __restrict__ aggb,
           const u16* __restrict__ wihb, const u16* __restrict__ whhb,
           const float* __restrict__ bih, const float* __restrict__ bhh){
    __shared__ u16x8 afragA[2048];   // 128 rows: [mtile4][kc8][lane64]
    __shared__ u16x8 afragX[2048];
    int tid = threadIdx.x;
    long r0 = (long)blockIdx.x * 128;
    const u16x8* aggp = (const u16x8*)aggb;
    const u16x8* xbp  = (const u16x8*)xb;
    for (int c = tid; c < 4096; c += 512){
        int mat = c >> 11, cc = c & 2047;
        int row = cc >> 4, kc8 = cc & 15;
        u16x8 v = (mat ? xbp : aggp)[(r0 + row)*16 + kc8];
        int slot = ((row>>5)*8 + (kc8>>1))*64 + (row&31) + 32*(kc8&1);
        (mat ? afragX : afragA)[slot] = v;
    }
    __syncthreads();
    int w = tid >> 6, lane = tid & 63;
    int mtg = w >> 2;              // 0..1 -> rows mtg*64 .. mtg*64+63
    int cb  = (w & 3) * 32;        // col base within 128
    f32x16 acc0[6], acc1[6];
    #pragma unroll
    for (int t = 0; t < 6; t++){ acc0[t] = (f32x16)0.f; acc1[t] = (f32x16)0.f; }
    const u16x8* bi = (const u16x8*)wihb;
    const u16x8* bh = (const u16x8*)whhb;
    int kh = lane >> 5;
    int ncol = cb + (lane & 31);
    #pragma unroll
    for (int kc = 0; kc < 8; kc++){
        u16x8 aA0 = afragA[((2*mtg+0)*8 + kc)*64 + lane];
        u16x8 aA1 = afragA[((2*mtg+1)*8 + kc)*64 + lane];
        u16x8 aX0 = afragX[((2*mtg+0)*8 + kc)*64 + lane];
        u16x8 aX1 = afragX[((2*mtg+1)*8 + kc)*64 + lane];
        #pragma unroll
        for (int g3 = 0; g3 < 3; g3++){
            int n = g3*128 + ncol;
            u16x8 b1 = bi[n*16 + kc*2 + kh];
            u16x8 b2 = bh[n*16 + kc*2 + kh];
            acc0[g3]   = __builtin_amdgcn_mfma_f32_32x32x16_bf16(
                __builtin_bit_cast(bf16x8, aA0), __builtin_bit_cast(bf16x8, b1), acc0[g3], 0,0,0);
            acc1[g3]   = __builtin_amdgcn_mfma_f32_32x32x16_bf16(
                __builtin_bit_cast(bf16x8, aA1), __builtin_bit_cast(bf16x8, b1), acc1[g3], 0,0,0);
            acc0[3+g3] = __builtin_amdgcn_mfma_f32_32x32x16_bf16(
                __builtin_bit_cast(bf16x8, aX0), __builtin_bit_cast(bf16x8, b2), acc0[3+g3], 0,0,0);
            acc1[3+g3] = __builtin_amdgcn_mfma_f32_32x32x16_bf16(
                __builtin_bit_cast(bf16x8, aX1), __builtin_bit_cast(bf16x8, b2), acc1[3+g3], 0,0,0);
        }
    }
    // GRU elementwise in fp32; old x read from staged LDS fragments
    int col = cb + (lane & 31);
    float bir = bih[col], biz = bih[col+128], bin = bih[col+256];
    float bhr = bhh[col], bhz = bhh[col+128], bhn = bhh[col+256];
    int kc8c = col >> 3, elc = col & 7;
    #pragma unroll
    for (int mt2 = 0; mt2 < 2; mt2++){
        const f32x16* ac = mt2 ? acc1 : acc0;
        #pragma unroll
        for (int r = 0; r < 16; r++){
            int row = mtg*64 + mt2*32 + (r&3) + 8*(r>>2) + 4*kh;
            u16x8 xv = afragX[((row>>5)*8 + (kc8c>>1))*64 + (row&31) + 32*(kc8c&1)];
            float xo = bf2f(((const u16*)&xv)[elc]);
            float rr  = sigf(ac[0][r] + bir + ac[3][r] + bhr);
            float zz  = sigf(ac[1][r] + biz + ac[4][r] + bhz);
            float nn_ = tanhf(ac[2][r] + bin + rr*(ac[5][r] + bhn));
            float xn  = (1.f - zz)*nn_ + zz*xo;
            xb[(size_t)(r0 + row)*DIM + col] = f2bf(xn);
        }
    }
}

// ---------------------------------------------------------------------------
// ggnn_out = x @ transdim_w^T via MFMA (M x 64 fp32 out, K=128). Grid 1250 x 256.
__global__ void __launch_bounds__(256)
k_transdim(const u16* __restrict__ xb, const u16* __restrict__ twb, float* __restrict__ out){
    int tid = threadIdx.x;
    int w = tid >> 6, lane = tid & 63;
    int m = lane & 31, kh = lane >> 5;
    long r0 = (long)blockIdx.x * 128;
    const u16x8* xp = (const u16x8*)xb;
    const u16x8* tp = (const u16x8*)twb;
    long rowA = r0 + w*32 + m;
    f32x16 acc[2];
    acc[0] = (f32x16)0.f; acc[1] = (f32x16)0.f;
    #pragma unroll
    for (int kc = 0; kc < 8; kc++){
        u16x8 a = xp[rowA*16 + kc*2 + kh];
        #pragma unroll
        for (int nt = 0; nt < 2; nt++){
            u16x8 b = tp[(nt*32 + m)*16 + kc*2 + kh];
            acc[nt] = __builtin_amdgcn_mfma_f32_32x32x16_bf16(
                __builtin_bit_cast(bf16x8, a), __builtin_bit_cast(bf16x8, b), acc[nt], 0,0,0);
        }
    }
    #pragma unroll
    for (int nt = 0; nt < 2; nt++){
        #pragma unroll
        for (int r = 0; r < 16; r++){
            int row = w*32 + (r&3) + 8*(r>>2) + 4*kh;
            int col = nt*32 + m;
            out[(r0 + row)*DCN + col] = acc[nt][r];
        }
    }
}

// ---------------------------------------------------------------------------
// Attention + lstm_in assembly. One block per g.
__global__ void __launch_bounds__(256)
k_attention(const float* __restrict__ gout, const float* __restrict__ cemb,
            const float* __restrict__ cid, const float* __restrict__ conc,
            const float* __restrict__ curres, float* __restrict__ lstm_in){
    int g = blockIdx.x; int tid = threadIdx.x;
    __shared__ float gg[NNODE*65];
    __shared__ float ce_s[CP1N];
    __shared__ float q_s[DCN];
    __shared__ float sc[256];
    __shared__ float red[256];
    __shared__ float part[4][DCN];
    __shared__ float oacc[DCN];
    __shared__ float num_s;
    if (tid < CP1N) ce_s[tid] = cemb[(size_t)g*CP1N + tid];
    if (tid < DCN) oacc[tid] = 0.f;
    for (int i = tid; i < NNODE*DCN; i += 256){
        int n = i >> 6, d = i & 63;
        gg[n*65 + d] = gout[((size_t)g*NNODE + n)*DCN + d];
    }
    red[tid] = (tid < CP1N) ? cid[(size_t)g*CP1N + tid] : 0.f;
    __syncthreads();
    for (int s = 128; s > 0; s >>= 1){ if (tid < s) red[tid] += red[tid+s]; __syncthreads(); }
    if (tid == 0){ float nm = red[0]; num_s = (nm == 0.f) ? 1.f : nm; }
    __syncthreads();
    for (int c = 0; c < CP1N; c++){
        float ce = ce_s[c];
        if (ce == 0.f) continue;          // uniform across block
        if (tid < DCN) q_s[tid] = ce * conc[c*DCN + tid];
        __syncthreads();
        float s = 0.f;
        if (tid < NNODE){
            const float* gr_ = &gg[tid*65];
            #pragma unroll 16
            for (int d = 0; d < DCN; d++) s += q_s[d] * gr_[d];
        }
        red[tid] = (tid < NNODE) ? s : -1e30f;
        __syncthreads();
        for (int t2 = 128; t2 > 0; t2 >>= 1){ if (tid < t2) red[tid] = fmaxf(red[tid], red[tid+t2]); __syncthreads(); }
        float mx = red[0];
        __syncthreads();
        float e = (tid < NNODE) ? expf(s - mx) : 0.f;
        sc[tid] = e;
        red[tid] = e;
        __syncthreads();
        for (int t2 = 128; t2 > 0; t2 >>= 1){ if (tid < t2) red[tid] += red[tid+t2]; __syncthreads(); }
        float inv = ce / red[0];
        int d = tid & 63, ngp = tid >> 6;
        float pa = 0.f;
        for (int n = ngp; n < NNODE; n += 4) pa += sc[n] * gg[n*65 + d];
        part[ngp][d] = pa;
        __syncthreads();
        if (tid < DCN) oacc[tid] += inv * (part[0][tid] + part[1][tid] + part[2][tid] + part[3][tid]);
        __syncthreads();
    }
    if (tid < FEATN){
        float v;
        if      (tid < CP1N)       v = ce_s[tid];
        else if (tid < CP1N+DCN)   v = oacc[tid-CP1N] / num_s;
        else                       v = curres[(size_t)g*2 + (tid-CP1N-DCN)];
        lstm_in[(size_t)g*FEATN + tid] = v;
    }
}

// ---------------------------------------------------------------------------
// gi_all = lstm_in @ Wih^T + (bih + bhh)    (800 x 1024, K=177)
__global__ void __launch_bounds__(256)
k_gi(const float* __restrict__ lstm_in, const float* __restrict__ wihT,
     const float* __restrict__ bih, const float* __restrict__ bhh, float* __restrict__ gi){
    int rb = blockIdx.x;   // 100 blocks of 8 rows
    int jb = blockIdx.y;   // 4
    int tid = threadIdx.x;
    __shared__ float in_s[8][FEATN];
    for (int i = tid; i < 8*FEATN; i += 256){ int r = i/FEATN, k = i%FEATN; in_s[r][k] = lstm_in[((size_t)rb*8+r)*FEATN + k]; }
    __syncthreads();
    int j = jb*256 + tid;
    float acc[8];
    #pragma unroll
    for (int i = 0; i < 8; i++) acc[i] = 0.f;
    for (int k = 0; k < FEATN; k++){
        float w = wihT[(size_t)k*1024 + j];
        #pragma unroll
        for (int i = 0; i < 8; i++) acc[i] += in_s[i][k] * w;
    }
    float b = bih[j] + bhh[j];
    #pragma unroll
    for (int i = 0; i < 8; i++) gi[((size_t)rb*8+i)*1024 + j] = acc[i] + b;
}

// ---------------------------------------------------------------------------
// Sequential LSTM: one block per batch item. Whh CU-resident:
// 104 bf16-pairs/thread in VGPRs + 24 pairs in LDS packed as uint4.
static const int WREG = 104;
static const int WL4  = 6;    // 24 pairs = 6 uint4 groups (pairs 104..127)

__global__ void __launch_bounds__(1024)
__attribute__((amdgpu_waves_per_eu(4,4)))
k_lstm(const float* __restrict__ gi, const unsigned* __restrict__ whhP, float* __restrict__ out){
    int b = blockIdx.x; int tid = threadIdx.x;
    __shared__ uint4 ldsw4[WL4][1024];       // 96 KB
    __shared__ float gates[1024];
    __shared__ __align__(8) u16 h16[HID];    // packed bf16 h, read as u32 pairs
    unsigned wreg[WREG];
    #pragma unroll
    for (int i = 0; i < WREG; i++) wreg[i] = whhP[(size_t)i*1024 + tid];
    #pragma unroll
    for (int q = 0; q < WL4; q++){
        uint4 v;
        v.x = whhP[(size_t)(WREG + 4*q + 0)*1024 + tid];
        v.y = whhP[(size_t)(WREG + 4*q + 1)*1024 + tid];
        v.z = whhP[(size_t)(WREG + 4*q + 2)*1024 + tid];
        v.w = whhP[(size_t)(WREG + 4*q + 3)*1024 + tid];
        ldsw4[q][tid] = v;
    }
    if (tid < 128) ((unsigned*)h16)[tid] = 0u;
    float c_reg = 0.f;
    int lane = tid & 63;
    __syncthreads();
    float giv = gi[(size_t)b*SLN*1024 + tid];
    for (int t = 0; t < SLN; t++){
        unsigned hv0 = ((const unsigned*)h16)[lane];
        unsigned hv1 = ((const unsigned*)h16)[64 + lane];
        float acc0 = giv, acc1 = 0.f;
        if (t+1 < SLN) giv = gi[((size_t)b*SLN + t + 1)*1024 + tid];
        #pragma unroll
        for (int p = 0; p < 64; p += 2){
            unsigned hpa = (unsigned)__builtin_amdgcn_readlane((int)hv0, p);
            unsigned hpb = (unsigned)__builtin_amdgcn_readlane((int)hv0, p+1);
            acc0 = dot2bf(wreg[p],   hpa, acc0);
            acc1 = dot2bf(wreg[p+1], hpb, acc1);
        }
        #pragma unroll
        for (int p = 64; p < WREG; p += 2){
            unsigned hpa = (unsigned)__builtin_amdgcn_readlane((int)hv1, p - 64);
            unsigned hpb = (unsigned)__builtin_amdgcn_readlane((int)hv1, p - 63);
            acc0 = dot2bf(wreg[p],   hpa, acc0);
            acc1 = dot2bf(wreg[p+1], hpb, acc1);
        }
        #pragma unroll
        for (int q = 0; q < WL4; q++){
            uint4 wv = ldsw4[q][tid];
            int base = WREG + 4*q - 64;
            unsigned h0 = (unsigned)__builtin_amdgcn_readlane((int)hv1, base + 0);
            unsigned h1 = (unsigned)__builtin_amdgcn_readlane((int)hv1, base + 1);
            unsigned h2 = (unsigned)__builtin_amdgcn_readlane((int)hv1, base + 2);
            unsigned h3 = (unsigned)__builtin_amdgcn_readlane((int)hv1, base + 3);
            acc0 = dot2bf(wv.x, h0, acc0);
            acc1 = dot2bf(wv.y, h1, acc1);
            acc0 = dot2bf(wv.z, h2, acc0);
            acc1 = dot2bf(wv.w, h3, acc1);
        }
        gates[tid] = acc0 + acc1;
        __syncthreads();
        if (tid < HID){
            float i_ = sigf(gates[tid]);
            float f_ = sigf(gates[tid+256]);
            float g_ = tanhf(gates[tid+512]);
            float o_ = sigf(gates[tid+768]);
            c_reg = f_*c_reg + i_*g_;
            float h = o_*tanhf(c_reg);
            out[((size_t)b*SLN + t)*HID + tid] = h;
            h16[tid] = f2bf(h);
        }
        __syncthreads();
    }
}

// ---------------------------------------------------------------------------
// pred + masked BCE per row; outputs sigmoid(fp), ft; atomics for loss sums.
__global__ void __launch_bounds__(128)
k_final(const float* __restrict__ lstm_out, const float* __restrict__ pw, const float* __restrict__ pb,
        const float* __restrict__ tc, const float* __restrict__ result,
        float* __restrict__ out, float* __restrict__ lacc){
    int row = blockIdx.x; int tid = threadIdx.x;
    __shared__ __align__(16) float h_s[HID];
    __shared__ float redv[128], redn[128];
    h_s[tid]       = lstm_out[(size_t)row*HID + tid];
    h_s[tid + 128] = lstm_out[(size_t)row*HID + tid + 128];
    __syncthreads();
    float v = 0.f, n = 0.f;
    if (tid < CP1N){
        float acc = pb[tid];
        const float4* wr = (const float4*)(pw + (size_t)tid*HID);
        const float4* hp = (const float4*)h_s;
        #pragma unroll 8
        for (int k4 = 0; k4 < 64; k4++){
            float4 w = wr[k4]; float4 h4 = hp[k4];
            acc += h4.x*w.x + h4.y*w.y + h4.z*w.z + h4.w*w.w;
        }
        float t = tc[(size_t)row*CP1N + tid];
        v = acc*t; n = t;
    }
    redv[tid] = v; redn[tid] = n;
    __syncthreads();
    for (int s = 64; s > 0; s >>= 1){
        if (tid < s){ redv[tid] += redv[tid+s]; redn[tid] += redn[tid+s]; }
        __syncthreads();
    }
    if (tid == 0){
        float nc = redn[0];
        bool mask = nc > 0.f;
        float fp = redv[0] / (mask ? nc : 1.f);
        float ft = result[row];
        float bce = fmaxf(fp, 0.f) - fp*ft + log1pf(expf(-fabsf(fp)));
        out[1 + row]      = 1.f/(1.f + expf(-fp));
        out[1 + GN + row] = ft;
        if (mask){ atomicAdd(&lacc[0], bce); atomicAdd(&lacc[1], 1.f); }
    }
}

__global__ void k_loss_final(const float* __restrict__ lacc, float* __restrict__ out){
    out[0] = lacc[0] / fmaxf(lacc[1], 1.f);
}

// ---------------------------------------------------------------------------
extern "C" void kernel_launch(void* const* d_in, const int* in_sizes, int n_in,
                              void* d_out, int out_size, void* d_ws, size_t ws_size,
                              hipStream_t stream) {
    const float* c_id        = (const float*)d_in[1];
    const int*   node_id     = (const int*)  d_in[2];
    const int*   edge        = (const int*)  d_in[3];
    const int*   etype       = (const int*)  d_in[4];
    const float* target_c    = (const float*)d_in[5];
    const float* result      = (const float*)d_in[6];
    const float* c_embed     = (const float*)d_in[7];
    const float* cur_result  = (const float*)d_in[8];
    const float* node_emb_w  = (const float*)d_in[9];
    const float* edge_emb_w  = (const float*)d_in[10];
    const float* ggnn_w      = (const float*)d_in[11];
    const float* gru_w_ih    = (const float*)d_in[12];
    const float* gru_w_hh    = (const float*)d_in[13];
    const float* gru_b_ih    = (const float*)d_in[14];
    const float* gru_b_hh    = (const float*)d_in[15];
    const float* transdim_w  = (const float*)d_in[16];
    const float* concept     = (const float*)d_in[17];
    const float* lstm_w_ih   = (const float*)d_in[18];
    const float* lstm_w_hh   = (const float*)d_in[19];
    const float* lstm_b_ih   = (const float*)d_in[20];
    const float* lstm_b_hh   = (const float*)d_in[21];
    const float* pred_w      = (const float*)d_in[22];
    const float* pred_b      = (const float*)d_in[23];
    float* out = (float*)d_out;

    char* ws = (char*)d_ws;
    size_t off = 0;
    auto alloc = [&](size_t bytes) -> void* {
        void* p = ws + off;
        off += (bytes + 255) & ~(size_t)255;
        return p;
    };
    u16*      xb       = (u16*)     alloc((size_t)MROW*DIM*2);
    u16*      aggb     = (u16*)     alloc((size_t)MROW*DIM*2);
    int*      csr_src  = (int*)     alloc((size_t)GN*NEDGE*4);
    float*    csr_w    = (float*)   alloc((size_t)GN*NEDGE*4);
    int*      csr_off  = (int*)     alloc((size_t)GN*(NNODE+1)*4);
    float*    lstm_in  = (float*)   alloc((size_t)GN*FEATN*4);
    float*    gi       = (float*)   alloc((size_t)GN*1024*4);
    unsigned* whhP     = (unsigned*)alloc((size_t)128*1024*4);
    float*    wihT     = (float*)   alloc((size_t)FEATN*1024*4);
    float*    lstm_out = (float*)   alloc((size_t)GN*HID*4);
    u16*      wihb     = (u16*)     alloc((size_t)384*128*2);
    u16*      whhb     = (u16*)     alloc((size_t)384*128*2);
    u16*      gwTb     = (u16*)     alloc((size_t)4*128*128*2);
    u16*      twb      = (u16*)     alloc((size_t)DCN*DIM*2);
    float*    lacc     = (float*)   alloc(256);
    float*    ggnn_out = (float*)aggb;   // aggb (bf16, MROW*128*2 B) dead after layer 4; same byte size as MROW*64 fp32

    hipMemsetAsync(lacc, 0, 8, stream);
    {
        int total = 128*1024 + FEATN*1024;
        k_transpose_w<<<(total + 255)/256, 256, 0, stream>>>(lstm_w_hh, lstm_w_ih, whhP, wihT);
    }
    k_convert_w<<<672, 256, 0, stream>>>(gru_w_ih, gru_w_hh, ggnn_w, transdim_w, wihb, whhb, gwTb, twb);
    k_build_csr<<<GN, 256, 0, stream>>>(edge, etype, edge_emb_w, csr_src, csr_w, csr_off);
    k_gather_x<<<4096, 256, 0, stream>>>(node_id, (const float4*)node_emb_w, (u16x8*)xb);
    for (int l = 0; l < 4; l++){
        k_mm_scatter<<<GN, 256, 0, stream>>>(xb, gwTb + (size_t)l*DIM*DIM,
                                             csr_src, csr_w, csr_off, aggb);
        k_gru_mfma<<<MROW/128, 512, 0, stream>>>(xb, aggb, wihb, whhb, gru_b_ih, gru_b_hh);
    }
    k_transdim<<<MROW/128, 256, 0, stream>>>(xb, twb, ggnn_out);
    k_attention<<<GN, 256, 0, stream>>>(ggnn_out, c_embed, c_id, concept, cur_result, lstm_in);
    k_gi<<<dim3(100, 4), 256, 0, stream>>>(lstm_in, wihT, lstm_b_ih, lstm_b_hh, gi);
    k_lstm<<<BSZ, 1024, 0, stream>>>(gi, whhP, lstm_out);
    k_final<<<GN, 128, 0, stream>>>(lstm_out, pred_w, pred_b, target_c, result, out, lacc);
    k_loss_final<<<1, 1, 0, stream>>>(lacc, out);
}